// Round 14
// baseline (1049.640 us; speedup 1.0000x reference)
//
#include <hip/hip_runtime.h>
#include <cstdint>
#include <cstddef>
#include <cmath>

#define B_ 8192
#define D_ 1024
#define H_ 2048
#define O_ 1024
#define E_ 8

typedef __bf16 bf16;
typedef __bf16 bf16x8 __attribute__((ext_vector_type(8)));
typedef __bf16 bf16x4v __attribute__((ext_vector_type(4)));
typedef float f32x4 __attribute__((ext_vector_type(4)));
typedef float f32x16 __attribute__((ext_vector_type(16)));

typedef __attribute__((address_space(1))) void gvoid;
typedef __attribute__((address_space(3))) void lvoid;

__device__ __forceinline__ void gload16(const void* g, void* l) {
  __builtin_amdgcn_global_load_lds((gvoid*)g, (lvoid*)l, 16u, 0, 0);
}

// Abramowitz-Stegun 7.1.26 rational erf, |eps| <= 1.5e-7.
__device__ __forceinline__ float fast_erff(float x) {
  float ax = __builtin_fabsf(x);
  float t = 1.f / (1.f + 0.3275911f * ax);
  float p = t * (0.254829592f +
            t * (-0.284496736f +
            t * (1.421413741f +
            t * (-1.453152027f +
            t * 1.061405429f))));
  float r = 1.f - p * __expf(-ax * ax);
  return __builtin_copysignf(r, x);
}
__device__ __forceinline__ float gelu_exact(float v) {
  return 0.5f * v * (1.f + fast_erff(v * 0.70710678118654752f));
}

// w: [E][R][C] f32 row-major  ->  wt: [E][C][R] bf16
__global__ __launch_bounds__(256) void transpose_w_kernel(const float* __restrict__ w,
                                                          bf16* __restrict__ wt,
                                                          int R, int C) {
  __shared__ float tile[32][33];
  int e = blockIdx.z;
  int c0 = blockIdx.x * 32, r0 = blockIdx.y * 32;
  int tx = threadIdx.x, ty = threadIdx.y;  // 32 x 8
  const float* we = w + (size_t)e * R * C;
  bf16* wte = wt + (size_t)e * R * C;
#pragma unroll
  for (int k = 0; k < 4; ++k) {
    int r = ty + 8 * k;
    tile[r][tx] = we[(size_t)(r0 + r) * C + c0 + tx];
  }
  __syncthreads();
#pragma unroll
  for (int k = 0; k < 4; ++k) {
    int c = ty + 8 * k;
    wte[(size_t)(c0 + c) * R + r0 + tx] = (bf16)tile[tx][c];
  }
}

// ---------------------------------------------------------------- gating
// convert_x fused in (R9); float4-vectorized (R10).
__global__ __launch_bounds__(256) void gating_kernel(const float* __restrict__ x,
                                                     const float* __restrict__ gw,
                                                     const float* __restrict__ gb,
                                                     bf16* __restrict__ xb,
                                                     float* __restrict__ probs,
                                                     float* __restrict__ wts,
                                                     float* __restrict__ ent) {
  int w = threadIdx.x >> 6, l = threadIdx.x & 63;
  int b = blockIdx.x * 4 + w;
  const float* xr = x + (size_t)b * D_;
  bf16* xbr = xb + (size_t)b * D_;
  float acc[E_];
#pragma unroll
  for (int e = 0; e < E_; ++e) acc[e] = 0.f;
#pragma unroll
  for (int j = 0; j < D_ / 256; ++j) {          // 4 iters, float4 per lane
    int d4 = j * 64 + l;
    float4 xv = ((const float4*)xr)[d4];
    bf16x4v o;
    o[0] = (bf16)xv.x; o[1] = (bf16)xv.y; o[2] = (bf16)xv.z; o[3] = (bf16)xv.w;
    ((bf16x4v*)xbr)[d4] = o;
    const float4* g = (const float4*)(gw + (size_t)(d4 * 4) * E_);  // 4 rows x 2 float4
    float xe[4] = {xv.x, xv.y, xv.z, xv.w};
#pragma unroll
    for (int k = 0; k < 4; ++k) {
      float4 g0 = g[k * 2], g1 = g[k * 2 + 1];
      acc[0] += xe[k] * g0.x; acc[1] += xe[k] * g0.y;
      acc[2] += xe[k] * g0.z; acc[3] += xe[k] * g0.w;
      acc[4] += xe[k] * g1.x; acc[5] += xe[k] * g1.y;
      acc[6] += xe[k] * g1.z; acc[7] += xe[k] * g1.w;
    }
  }
#pragma unroll
  for (int off = 32; off; off >>= 1)
#pragma unroll
    for (int e = 0; e < E_; ++e) acc[e] += __shfl_down(acc[e], off);

  if (l == 0) {
    float lg[E_], p[E_];
    float mx = -1e30f;
#pragma unroll
    for (int e = 0; e < E_; ++e) { lg[e] = acc[e] + gb[e]; mx = fmaxf(mx, lg[e]); }
    float s = 0.f;
#pragma unroll
    for (int e = 0; e < E_; ++e) { p[e] = expf(lg[e] - mx); s += p[e]; }
    float inv = 1.f / s;
    float en = 0.f;
#pragma unroll
    for (int e = 0; e < E_; ++e) { p[e] *= inv; en -= p[e] * logf(p[e] + 1e-8f); }
    ent[b] = en;
#pragma unroll
    for (int e = 0; e < E_; ++e) probs[(size_t)b * E_ + e] = p[e];
    int idx[E_]; float ps[E_];
#pragma unroll
    for (int e = 0; e < E_; ++e) { idx[e] = e; ps[e] = p[e]; }
    for (int i = 0; i < E_ - 1; ++i)
      for (int j = 0; j < E_ - 1 - i; ++j)
        if (ps[j] < ps[j + 1]) {
          float tp = ps[j]; ps[j] = ps[j + 1]; ps[j + 1] = tp;
          int ti = idx[j]; idx[j] = idx[j + 1]; idx[j + 1] = ti;
        }
    float cum = 0.f; float mp[E_];
#pragma unroll
    for (int e = 0; e < E_; ++e) mp[e] = 0.f;
    for (int i = 0; i < E_; ++i) {
      cum += ps[i];
      bool m = (cum <= 0.9f) || (i == 0);
      if (m) mp[idx[i]] = ps[i];
    }
    float ssum = 0.f;
#pragma unroll
    for (int e = 0; e < E_; ++e) ssum += mp[e];
    float invs = 1.f / (ssum + 1e-8f);
#pragma unroll
    for (int e = 0; e < E_; ++e) wts[(size_t)b * E_ + e] = mp[e] * invs;
  }
}

// ---------------------------------------------------------------- GEMM mainloop (16x16x32)
// Register-staged pipeline (best verified): global_load -> VGPR, ds_write after
// the barrier; loads in flight across a full compute phase. BK=64, 128x128 tile,
// 4 waves 2x2, 32 MFMA/iter. LDS [row][64] bf16 with p^(r&7) chunk swizzle.
__device__ __forceinline__ void gemm_loop_rs(const bf16* __restrict__ A,
                                             const bf16* __restrict__ Bt,
                                             int K, int rowBase, int colBase,
                                             bf16* lA, bf16* lB, f32x4 acc[4][4]) {
  const int tid = threadIdx.x;
  const int w = tid >> 6, l = tid & 63;
  const int wm = w >> 1, wn = w & 1;
  const int fm = l & 15, fc = l >> 4;
  const int lr = l >> 3;          // staging row-within-8
  const int lc = l & 7;           // global chunk (contiguous)
  const bf16* gA = A + (size_t)(rowBase + w * 32 + lr) * K + lc * 8;
  const bf16* gB = Bt + (size_t)(colBase + w * 32 + lr) * K + lc * 8;
  const int wp = lc ^ lr;         // LDS chunk position (row&7 == lr)
  bf16* dA = lA + (w * 32 + lr) * 64 + wp * 8;
  bf16* dB = lB + (w * 32 + lr) * 64 + wp * 8;

  bf16x8 ra[4], rb[4];
  const int nIter = K >> 6;
  // prologue: loads for iter 0
#pragma unroll
  for (int i = 0; i < 4; ++i) {
    ra[i] = *(const bf16x8*)(gA + (size_t)(i * 8) * K);
    rb[i] = *(const bf16x8*)(gB + (size_t)(i * 8) * K);
  }
  for (int it = 0; it < nIter; ++it) {
    __syncthreads();                    // prev compute done reading LDS
#pragma unroll
    for (int i = 0; i < 4; ++i) {       // vmcnt wait lands here (covered)
      *(bf16x8*)(dA + i * 512) = ra[i];
      *(bf16x8*)(dB + i * 512) = rb[i];
    }
    if (it + 1 < nIter) {
      const int k0 = (it + 1) << 6;
#pragma unroll
      for (int i = 0; i < 4; ++i) {     // in flight across full compute phase
        ra[i] = *(const bf16x8*)(gA + (size_t)(i * 8) * K + k0);
        rb[i] = *(const bf16x8*)(gB + (size_t)(i * 8) * K + k0);
      }
    }
    __syncthreads();                    // ds_writes visible
#pragma unroll
    for (int kh = 0; kh < 2; ++kh) {
      bf16x8 af[4], bb[4];
#pragma unroll
      for (int mt = 0; mt < 4; ++mt) {
        int r = wm * 64 + mt * 16 + fm;
        int pos = (kh * 4 + fc) ^ (r & 7);
        af[mt] = *(const bf16x8*)(lA + r * 64 + pos * 8);
      }
#pragma unroll
      for (int nt = 0; nt < 4; ++nt) {
        int r = wn * 64 + nt * 16 + fm;
        int pos = (kh * 4 + fc) ^ (r & 7);
        bb[nt] = *(const bf16x8*)(lB + r * 64 + pos * 8);
      }
#pragma unroll
      for (int mt = 0; mt < 4; ++mt)
#pragma unroll
        for (int nt = 0; nt < 4; ++nt)
          acc[mt][nt] = __builtin_amdgcn_mfma_f32_16x16x32_bf16(af[mt], bb[nt], acc[mt][nt], 0, 0, 0);
    }
  }
}

// ---------------------------------------------------------------- GEMM mainloop (32x32x16)
// R13: last untested structural lever. Same staging/LDS/swizzle as gemm_loop_rs;
// compute uses mfma_f32_32x32x16_bf16 (ubench 2382 vs 2075 TF; half the MFMA
// instruction count at identical LDS traffic). Wave computes 64x64 = 2x2 of
// 32x32; per BK=64: 4 ksteps of K=16, 16 MFMA. A/B operand layout (analog of
// the proven 16x16 mapping l&15 / l>>4): lane holds row l&31, K-octet l>>5;
// per-kstep chunk c = ks*2 + (l>>5), read at pos = c ^ (r&7) (conflict-free:
// pos spans all 8 slots per 8-row group).
__device__ __forceinline__ void gemm_loop_rs32(const bf16* __restrict__ A,
                                               const bf16* __restrict__ Bt,
                                               int K, int rowBase, int colBase,
                                               bf16* lA, bf16* lB, f32x16 acc[2][2]) {
  const int tid = threadIdx.x;
  const int w = tid >> 6, l = tid & 63;
  const int wm = w >> 1, wn = w & 1;
  const int am = l & 31;          // fragment row within 32-tile
  const int ko = l >> 5;          // K-octet (0/1) within K=16
  const int lr = l >> 3;          // staging row-within-8
  const int lc = l & 7;           // global chunk (contiguous)
  const bf16* gA = A + (size_t)(rowBase + w * 32 + lr) * K + lc * 8;
  const bf16* gB = Bt + (size_t)(colBase + w * 32 + lr) * K + lc * 8;
  const int wp = lc ^ lr;         // LDS chunk position (row&7 == lr)
  bf16* dA = lA + (w * 32 + lr) * 64 + wp * 8;
  bf16* dB = lB + (w * 32 + lr) * 64 + wp * 8;

  bf16x8 ra[4], rb[4];
  const int nIter = K >> 6;
#pragma unroll
  for (int i = 0; i < 4; ++i) {
    ra[i] = *(const bf16x8*)(gA + (size_t)(i * 8) * K);
    rb[i] = *(const bf16x8*)(gB + (size_t)(i * 8) * K);
  }
  for (int it = 0; it < nIter; ++it) {
    __syncthreads();                    // prev compute done reading LDS
#pragma unroll
    for (int i = 0; i < 4; ++i) {
      *(bf16x8*)(dA + i * 512) = ra[i];
      *(bf16x8*)(dB + i * 512) = rb[i];
    }
    if (it + 1 < nIter) {
      const int k0 = (it + 1) << 6;
#pragma unroll
      for (int i = 0; i < 4; ++i) {
        ra[i] = *(const bf16x8*)(gA + (size_t)(i * 8) * K + k0);
        rb[i] = *(const bf16x8*)(gB + (size_t)(i * 8) * K + k0);
      }
    }
    __syncthreads();                    // ds_writes visible
#pragma unroll
    for (int ks = 0; ks < 4; ++ks) {
      bf16x8 af[2], bb[2];
#pragma unroll
      for (int tm = 0; tm < 2; ++tm) {
        int r = wm * 64 + tm * 32 + am;
        int pos = (ks * 2 + ko) ^ (r & 7);
        af[tm] = *(const bf16x8*)(lA + r * 64 + pos * 8);
      }
#pragma unroll
      for (int tn = 0; tn < 2; ++tn) {
        int r = wn * 64 + tn * 32 + am;
        int pos = (ks * 2 + ko) ^ (r & 7);
        bb[tn] = *(const bf16x8*)(lB + r * 64 + pos * 8);
      }
#pragma unroll
      for (int tm = 0; tm < 2; ++tm)
#pragma unroll
        for (int tn = 0; tn < 2; ++tn)
          acc[tm][tn] = __builtin_amdgcn_mfma_f32_32x32x16_bf16(af[tm], bb[tn], acc[tm][tn], 0, 0, 0);
    }
  }
}

// ------------------------------------------------- v18 path (chunked over B)
// NC=2/SPLIT=4, col-pinned XCD map (measured optima). 32 KiB smem (pow-2 rule).
// gemm1 unchanged (proven 16x16 path + GELU epilogue).
__global__ __launch_bounds__(256, 4) void gemm1_v16_kernel(const bf16* __restrict__ xb,
                                                           const bf16* __restrict__ w1t,
                                                           const float* __restrict__ b1,
                                                           const float* __restrict__ wts,
                                                           bf16* __restrict__ h_chunk,
                                                           float* __restrict__ hsum,
                                                           int rowOffset, int Bc) {
  __shared__ bf16 smem[16384];          // 32 KiB: K-loop lA|lB; epi 128x128 swz
  bf16* lA = smem;
  bf16* lB = smem + 8192;
  f32x4 acc[4][4];
#pragma unroll
  for (int mt = 0; mt < 4; ++mt)
#pragma unroll
    for (int nt = 0; nt < 4; ++nt) acc[mt][nt] = 0.f;

  const int flat = blockIdx.y * 128 + blockIdx.x;
  const int xcd = flat & 7, lin = flat >> 3;
  const int cb = xcd * 16 + (lin & 15);
  const int rb = lin >> 4;
  const int colBase = cb * 128;               // fat col in [0,16384)
  const int rowLocal = rb * 128;
  const int rowGlobal = rowOffset + rowLocal;
  const int e = colBase >> 11;                // == xcd

  gemm_loop_rs(xb, w1t, D_, rowGlobal, colBase, lA, lB, acc);

  const int tid = threadIdx.x;
  const int w = tid >> 6, l = tid & 63;
  const int wm = w >> 1, wn = w & 1;
  const int fm = l & 15, fc = l >> 4;
  bf16* he = h_chunk + (size_t)e * Bc * H_;
  const int hc0 = colBase & (H_ - 1);

  float wgt[4][4];
#pragma unroll
  for (int mt = 0; mt < 4; ++mt)
#pragma unroll
    for (int i = 0; i < 4; ++i) {
      int gr = rowGlobal + wm * 64 + mt * 16 + fc * 4 + i;
      wgt[mt][i] = wts[(size_t)gr * E_ + e];
    }

  __syncthreads();   // K-loop LDS reads done; smem reused as epilogue stage
#pragma unroll
  for (int nt = 0; nt < 4; ++nt) {
    int c = wn * 64 + nt * 16 + fm;             // tile-local col
    float bias = b1[colBase + c];
    float csum = 0.f;
#pragma unroll
    for (int mt = 0; mt < 4; ++mt) {
      int rbse = wm * 64 + mt * 16 + fc * 4;    // tile-local row base
#pragma unroll
      for (int i = 0; i < 4; ++i) {
        int r = rbse + i;
        float v = gelu_exact(acc[mt][nt][i] + bias);
        csum += v;
        smem[(size_t)r * 128 + (((c >> 3) ^ (r & 7)) << 3) + (c & 7)] = (bf16)(v * wgt[mt][i]);
      }
    }
    csum += __shfl_down(csum, 32);
    csum += __shfl_down(csum, 16);
    if (fc == 0) atomicAdd(&hsum[colBase + c], csum);
  }
  __syncthreads();

  // coalesced store: per j, 16 rows x 256 B dense (swizzle-inverted read)
#pragma unroll
  for (int j = 0; j < 8; ++j) {
    int row = j * 16 + (tid >> 4);
    int cchunk = tid & 15;
    bf16x8 v = *(const bf16x8*)(smem + (size_t)row * 128 + (size_t)(cchunk ^ (row & 7)) * 8);
    *(bf16x8*)(he + (size_t)(rowLocal + row) * H_ + hc0 + cchunk * 8) = v;
  }
}

// GEMM2 (v18): 32x32x16 MFMA path. out_chunk += sum over split's experts of
// h_scaled[e] @ w2t[e]; s==0 adds sum_e wts*b2. Col-pinned grid (blockIdx.x ==
// col -> per-XCD w2t slice L2-resident; measured best of 3 mappings).
// C/D layout (HW-verified, m74/m101): col = lane&31,
// row = (reg&3) + 8*(reg>>2) + 4*(lane>>5), reg in [0,16).
template <int SPLIT>
__global__ __launch_bounds__(256, 4) void gemm2_v18_kernel(const bf16* __restrict__ h_chunk,
                                                           const bf16* __restrict__ w2t,
                                                           const float* __restrict__ b2,
                                                           const float* __restrict__ wts,
                                                           float* __restrict__ out_chunk,
                                                           int rowOffset, int Bc) {
  __shared__ bf16 smem[16384];
  bf16* lA = smem;
  bf16* lB = smem + 8192;
  f32x16 acc[2][2];
#pragma unroll
  for (int tm = 0; tm < 2; ++tm)
#pragma unroll
    for (int tn = 0; tn < 2; ++tn) acc[tm][tn] = 0.f;

  const int colBase = blockIdx.x * 128;
  const int rowLocal = blockIdx.y * 128;
  const int s = blockIdx.z;
  const int g = E_ / SPLIT, e0 = s * g;

  for (int e = e0; e < e0 + g; ++e)
    gemm_loop_rs32(h_chunk + (size_t)e * Bc * H_, w2t + (size_t)e * O_ * H_, H_,
                   rowLocal, colBase, lA, lB, acc);

  const int w = threadIdx.x >> 6, l = threadIdx.x & 63;
  const int wm = w >> 1, wn = w & 1;
  const int rhi = 4 * (l >> 5);             // row offset from lane bit 5
#pragma unroll
  for (int tn = 0; tn < 2; ++tn) {
    const int gc = colBase + wn * 64 + tn * 32 + (l & 31);
    float b2v[E_];
    if (s == 0) {
#pragma unroll
      for (int ee = 0; ee < E_; ++ee) b2v[ee] = b2[(size_t)ee * O_ + gc];
    }
#pragma unroll
    for (int tm = 0; tm < 2; ++tm) {
      const int rbase = rowLocal + wm * 64 + tm * 32 + rhi;
#pragma unroll
      for (int reg = 0; reg < 16; ++reg) {
        const int lr2 = rbase + (reg & 3) + 8 * (reg >> 2);
        float v = acc[tm][tn][reg];
        if (s == 0) {
          const float4* wr = (const float4*)(wts + (size_t)(rowOffset + lr2) * E_);
          float4 w0 = wr[0], w1v = wr[1];
          v += w0.x * b2v[0] + w0.y * b2v[1] + w0.z * b2v[2] + w0.w * b2v[3] +
               w1v.x * b2v[4] + w1v.y * b2v[5] + w1v.z * b2v[6] + w1v.w * b2v[7];
        }
        float* op = out_chunk + (size_t)lr2 * O_ + gc;
        if (SPLIT == 1) *op = v;
        else atomicAdd(op, v);
      }
    }
  }
}

// esum2[e][o] += hsum[e, seg] . w2[e, seg, o]  (parallel over 8 H-segments;
// esum2 zeroed first).
__global__ __launch_bounds__(256) void esum_v2_kernel(const float* __restrict__ hsum,
                                                      const float* __restrict__ w2,
                                                      float* __restrict__ esum2) {
  const int e = blockIdx.y;
  const int o = blockIdx.x * 256 + threadIdx.x;
  const int h0 = blockIdx.z * (H_ / 8);
  const float* w2e = w2 + (size_t)e * H_ * O_;
  const float* hs = hsum + (size_t)e * H_;
  float a0 = 0.f, a1 = 0.f;
  for (int h = h0; h < h0 + H_ / 8; h += 2) {
    a0 += hs[h] * w2e[(size_t)h * O_ + o];
    a1 += hs[h + 1] * w2e[(size_t)(h + 1) * O_ + o];
  }
  atomicAdd(&esum2[(size_t)e * O_ + o], a0 + a1);
}

// ---------------------------------------------------------------- fallback GEMMs
__device__ __forceinline__ void gemm_loop(const bf16* __restrict__ A,
                                          const bf16* __restrict__ Bt,
                                          int K, int rowBase, int colBase,
                                          bf16* lA, bf16* lB, f32x4 acc[4][4]) {
  const int tid = threadIdx.x;
  const int w = tid >> 6, l = tid & 63;
  const int wm = w >> 1, wn = w & 1;
  const int fm = l & 15, fc = l >> 4;
  const int lr = l >> 2, lc = l & 3;
  const int sr0 = (w * 2 + 0) * 16 + lr;
  const int sr1 = (w * 2 + 1) * 16 + lr;
  const int cg0 = lc ^ ((sr0 >> 1) & 3);
  const int cg1 = lc ^ ((sr1 >> 1) & 3);
  const bf16* gA0 = A + (size_t)(rowBase + sr0) * K + cg0 * 8;
  const bf16* gA1 = A + (size_t)(rowBase + sr1) * K + cg1 * 8;
  const bf16* gB0 = Bt + (size_t)(colBase + sr0) * K + cg0 * 8;
  const bf16* gB1 = Bt + (size_t)(colBase + sr1) * K + cg1 * 8;
  bf16* lA0 = lA + (w * 2 + 0) * 512;
  bf16* lA1 = lA + (w * 2 + 1) * 512;
  bf16* lB0 = lB + (w * 2 + 0) * 512;
  bf16* lB1 = lB + (w * 2 + 1) * 512;

  for (int k0 = 0; k0 < K; k0 += 32) {
    __syncthreads();
    gload16(gA0 + k0, lA0);
    gload16(gA1 + k0, lA1);
    gload16(gB0 + k0, lB0);
    gload16(gB1 + k0, lB1);
    __syncthreads();

    bf16x8 af[4], bb[4];
#pragma unroll
    for (int mt = 0; mt < 4; ++mt) {
      int r = wm * 64 + mt * 16 + fm;
      af[mt] = *(const bf16x8*)(lA + (size_t)(r * 4 + (fc ^ ((r >> 1) & 3))) * 8);
    }
#pragma unroll
    for (int nt = 0; nt < 4; ++nt) {
      int r = wn * 64 + nt * 16 + fm;
      bb[nt] = *(const bf16x8*)(lB + (size_t)(r * 4 + (fc ^ ((r >> 1) & 3))) * 8);
    }
#pragma unroll
    for (int mt = 0; mt < 4; ++mt)
#pragma unroll
      for (int nt = 0; nt < 4; ++nt)
        acc[mt][nt] = __builtin_amdgcn_mfma_f32_16x16x32_bf16(af[mt], bb[nt], acc[mt][nt], 0, 0, 0);
  }
}

__global__ __launch_bounds__(256) void gemm1_gelu_kernel(const bf16* __restrict__ xb,
                                                         const bf16* __restrict__ w1te,
                                                         const float* __restrict__ b1e,
                                                         bf16* __restrict__ h) {
  __shared__ bf16 lA[128 * 32];
  __shared__ bf16 lB[128 * 32];
  f32x4 acc[4][4];
#pragma unroll
  for (int mt = 0; mt < 4; ++mt)
#pragma unroll
    for (int nt = 0; nt < 4; ++nt) acc[mt][nt] = 0.f;

  int rowBase = blockIdx.y * 128, colBase = blockIdx.x * 128;
  gemm_loop(xb, w1te, D_, rowBase, colBase, lA, lB, acc);

  const int w = threadIdx.x >> 6, l = threadIdx.x & 63;
  const int wm = w >> 1, wn = w & 1;
#pragma unroll
  for (int mt = 0; mt < 4; ++mt)
#pragma unroll
    for (int nt = 0; nt < 4; ++nt) {
      int gc = colBase + wn * 64 + nt * 16 + (l & 15);
      float bias = b1e[gc];
#pragma unroll
      for (int i = 0; i < 4; ++i) {
        int gr = rowBase + wm * 64 + mt * 16 + (l >> 4) * 4 + i;
        float v = gelu_exact(acc[mt][nt][i] + bias);
        h[(size_t)gr * H_ + gc] = (bf16)v;
      }
    }
}

__global__ __launch_bounds__(256) void gemm2_fused_kernel(const bf16* __restrict__ h,
                                                          const bf16* __restrict__ w2te,
                                                          const float* __restrict__ b2e,
                                                          const float* __restrict__ wts,
                                                          int e,
                                                          float* __restrict__ out,
                                                          float* __restrict__ esum) {
  __shared__ bf16 lA[128 * 32];
  __shared__ bf16 lB[128 * 32];
  f32x4 acc[4][4];
#pragma unroll
  for (int mt = 0; mt < 4; ++mt)
#pragma unroll
    for (int nt = 0; nt < 4; ++nt) acc[mt][nt] = 0.f;

  int rowBase = blockIdx.y * 128, colBase = blockIdx.x * 128;
  gemm_loop(h, w2te, H_, rowBase, colBase, lA, lB, acc);

  const int w = threadIdx.x >> 6, l = threadIdx.x & 63;
  const int wm = w >> 1, wn = w & 1;
#pragma unroll
  for (int nt = 0; nt < 4; ++nt) {
    int gc = colBase + wn * 64 + nt * 16 + (l & 15);
    float bias = b2e[gc];
    float csum = 0.f;
#pragma unroll
    for (int mt = 0; mt < 4; ++mt) {
      int grb = rowBase + wm * 64 + mt * 16 + (l >> 4) * 4;
#pragma unroll
      for (int i = 0; i < 4; ++i) {
        int gr = grb + i;
        float v = acc[mt][nt][i] + bias;
        csum += v;
        float wgt = wts[(size_t)gr * E_ + e];
        float* op = out + (size_t)gr * O_ + gc;
        *op += wgt * v;
      }
    }
    csum += __shfl_down(csum, 32);
    csum += __shfl_down(csum, 16);
    if ((l >> 4) == 0) atomicAdd(&esum[(size_t)e * O_ + gc], csum);
  }
}

// ---------------------------------------------------------------- losses
// MODE 0: expert_mean = esum/B (bias included). MODE 1: esum/B + b2.
template <int MODE>
__global__ __launch_bounds__(256) void scalars_kernel(const float* __restrict__ probs,
                                                      const float* __restrict__ ent,
                                                      const float* __restrict__ esum,
                                                      const float* __restrict__ b2,
                                                      float* __restrict__ outs) {
  __shared__ float red[256];
  __shared__ float Vsh[E_][O_ + 8];
  __shared__ float mp_sh[E_], norm_sh[E_];
  __shared__ float gram[E_][E_];
  int t = threadIdx.x;

  float s = 0.f;
  for (int i = t; i < B_; i += 256) s += ent[i];
  red[t] = s; __syncthreads();
  for (int off = 128; off; off >>= 1) { if (t < off) red[t] += red[t + off]; __syncthreads(); }
  if (t == 0) outs[0] = red[0] / (float)B_;
  __syncthreads();

  float mp[E_];
#pragma unroll
  for (int e = 0; e < E_; ++e) mp[e] = 0.f;
  for (int i = t; i < B_; i += 256) {
#pragma unroll
    for (int e = 0; e < E_; ++e) mp[e] += probs[(size_t)i * E_ + e];
  }
  for (int e = 0; e < E_; ++e) {
    red[t] = mp[e]; __syncthreads();
    for (int off = 128; off; off >>= 1) { if (t < off) red[t] += red[t + off]; __syncthreads(); }
    if (t == 0) mp_sh[e] = red[0] / (float)B_;
    __syncthreads();
  }

  for (int e = 0; e < E_; ++e) {
    float ss = 0.f;
    for (int o = t; o < O_; o += 256) {
      float m = esum[(size_t)e * O_ + o] / (float)B_;
      if (MODE == 1) m += b2[(size_t)e * O_ + o];
      ss += m * m;
    }
    red[t] = ss; __syncthreads();
    for (int off = 128; off; off >>= 1) { if (t < off) red[t] += red[t + off]; __syncthreads(); }
    if (t == 0) norm_sh[e] = sqrtf(red[0]) + 1e-6f;
    __syncthreads();
  }

  for (int e = 0; e < E_; ++e)
    for (int o = t; o < O_; o += 256) {
      float m = esum[(size_t)e * O_ + o] / (float)B_;
      if (MODE == 1) m += b2[(size_t)e * O_ + o];
      Vsh[e][o] = mp_sh[e] * m / norm_sh[e];
    }
  __syncthreads();

  {
    // 256 threads: pair p = t>>2 (i=p>>3, j=p&7), sub-range sub = t&3 over O/4.
    int pair = t >> 2, sub = t & 3;
    int i = pair >> 3, j = pair & 7;
    float g = 0.f;
    for (int o = sub * (O_ / 4); o < (sub + 1) * (O_ / 4); ++o)
      g += Vsh[i][o] * Vsh[j][o];
    red[t] = g; __syncthreads();
    if (sub == 0) {
      float gg = red[t] + red[t + 1] + red[t + 2] + red[t + 3];
      if (i == j) gg += 1e-6f;
      gram[i][j] = gg;
    }
  }
  __syncthreads();

  if (t == 0) {
    double a[E_][E_];
    for (int i = 0; i < E_; ++i) for (int j = 0; j < E_; ++j) a[i][j] = (double)gram[i][j];
    double ld = 0.0;
    for (int k = 0; k < E_; ++k) {
      int p = k; double mx = fabs(a[k][k]);
      for (int i = k + 1; i < E_; ++i) if (fabs(a[i][k]) > mx) { mx = fabs(a[i][k]); p = i; }
      if (p != k) for (int j = 0; j < E_; ++j) { double tmp = a[k][j]; a[k][j] = a[p][j]; a[p][j] = tmp; }
      ld += log(fabs(a[k][k]));
      double inv = 1.0 / a[k][k];
      for (int i = k + 1; i < E_; ++i) {
        double f = a[i][k] * inv;
        for (int j = k; j < E_; ++j) a[i][j] -= f * a[k][j];
      }
    }
    outs[1] = (float)(-ld);
  }
}

// ---------------------------------------------------------------- launch
extern "C" void kernel_launch(void* const* d_in, const int* in_sizes, int n_in,
                              void* d_out, int out_size, void* d_ws, size_t ws_size,
                              hipStream_t stream) {
  const float* x  = (const float*)d_in[0];
  const float* gw = (const float*)d_in[1];
  const float* gb = (const float*)d_in[2];
  const float* w1 = (const float*)d_in[3];
  const float* b1 = (const float*)d_in[4];
  const float* w2 = (const float*)d_in[5];
  const float* b2 = (const float*)d_in[6];
  float* out = (float*)d_out;

  char* ws = (char*)d_ws;
  size_t need = 0;
  bf16* xb    = (bf16*)(ws + need); need += (size_t)B_ * D_ * 2;
  bf16* w1t   = (bf16*)(ws + need); need += (size_t)E_ * D_ * H_ * 2;
  bf16* w2t   = (bf16*)(ws + need); need += (size_t)E_ * H_ * O_ * 2;
  float* wts  = (float*)(ws + need); need += (size_t)B_ * E_ * 4;
  float* probs= (float*)(ws + need); need += (size_t)B_ * E_ * 4;
  float* ent  = (float*)(ws + need); need += (size_t)B_ * 4;
  float* hsum = (float*)(ws + need); need += (size_t)E_ * H_ * 4;
  float* esum = (float*)(ws + need); need += (size_t)E_ * O_ * 4;
  size_t need_common = need;
  bf16* h_chunk = (bf16*)(ws + need);

  // NC preference 2 (measured optimum); fallbacks 4, 8, 1.
  int NC = 0;
  const int prefs[4] = {2, 4, 8, 1};
  for (int i = 0; i < 4; ++i) {
    int nc = prefs[i];
    size_t tot = need_common + (size_t)E_ * (B_ / nc) * H_ * 2;
    if (ws_size >= tot) { NC = nc; break; }
  }

  transpose_w_kernel<<<dim3(H_ / 32, D_ / 32, E_), dim3(32, 8), 0, stream>>>(w1, w1t, D_, H_);
  transpose_w_kernel<<<dim3(O_ / 32, H_ / 32, E_), dim3(32, 8), 0, stream>>>(w2, w2t, H_, O_);
  gating_kernel<<<B_ / 4, 256, 0, stream>>>(x, gw, gb, xb, probs, wts, ent);

  if (NC > 0) {
    const int Bc = B_ / NC;
    const int SPLIT = (NC == 1) ? 2 : (NC == 2) ? 4 : 8;
    // hsum and esum are adjacent in the workspace: one memset covers both.
    hipMemsetAsync(hsum, 0, (size_t)E_ * H_ * sizeof(float) + (size_t)E_ * O_ * sizeof(float), stream);
    hipMemsetAsync(out, 0, (size_t)B_ * O_ * sizeof(float), stream);
    for (int c = 0; c < NC; ++c) {
      int rowOffset = c * Bc;
      gemm1_v16_kernel<<<dim3(128, Bc / 128), 256, 0, stream>>>(
          xb, w1t, b1, wts, h_chunk, hsum, rowOffset, Bc);
      float* out_chunk = out + (size_t)rowOffset * O_;
      dim3 g2(O_ / 128, Bc / 128, SPLIT);
      switch (SPLIT) {
        case 2: gemm2_v18_kernel<2><<<g2, 256, 0, stream>>>(h_chunk, w2t, b2, wts, out_chunk, rowOffset, Bc); break;
        case 4: gemm2_v18_kernel<4><<<g2, 256, 0, stream>>>(h_chunk, w2t, b2, wts, out_chunk, rowOffset, Bc); break;
        case 8: gemm2_v18_kernel<8><<<g2, 256, 0, stream>>>(h_chunk, w2t, b2, wts, out_chunk, rowOffset, Bc); break;
      }
    }
    esum_v2_kernel<<<dim3(O_ / 256, E_, 8), 256, 0, stream>>>(hsum, w2, esum);
    scalars_kernel<1><<<1, 256, 0, stream>>>(probs, ent, esum, b2, out + (size_t)B_ * O_);
  } else {
    bf16* he = (bf16*)(ws + need_common);
    if (ws_size < need_common + (size_t)B_ * H_ * 2) return;
    hipMemsetAsync(out, 0, (size_t)B_ * O_ * sizeof(float), stream);
    hipMemsetAsync(esum, 0, (size_t)E_ * O_ * sizeof(float), stream);
    for (int e = 0; e < E_; ++e) {
      gemm1_gelu_kernel<<<dim3(H_ / 128, B_ / 128), 256, 0, stream>>>(
          xb, w1t + (size_t)e * H_ * D_, b1 + (size_t)e * H_, he);
      gemm2_fused_kernel<<<dim3(O_ / 128, B_ / 128), 256, 0, stream>>>(
          he, w2t + (size_t)e * O_ * H_, b2 + (size_t)e * O_, wts, e, out, esum);
    }
    scalars_kernel<0><<<1, 256, 0, stream>>>(probs, ent, esum, b2, out + (size_t)B_ * O_);
  }
}

// Round 15
// 1012.687 us; speedup vs baseline: 1.0365x; 1.0365x over previous
//
#include <hip/hip_runtime.h>
#include <cstdint>
#include <cstddef>
#include <cmath>

#define B_ 8192
#define D_ 1024
#define H_ 2048
#define O_ 1024
#define E_ 8

typedef __bf16 bf16;
typedef __bf16 bf16x8 __attribute__((ext_vector_type(8)));
typedef __bf16 bf16x4v __attribute__((ext_vector_type(4)));
typedef float f32x4 __attribute__((ext_vector_type(4)));

typedef __attribute__((address_space(1))) void gvoid;
typedef __attribute__((address_space(3))) void lvoid;

__device__ __forceinline__ void gload16(const void* g, void* l) {
  __builtin_amdgcn_global_load_lds((gvoid*)g, (lvoid*)l, 16u, 0, 0);
}

// Abramowitz-Stegun 7.1.26 rational erf, |eps| <= 1.5e-7.
__device__ __forceinline__ float fast_erff(float x) {
  float ax = __builtin_fabsf(x);
  float t = 1.f / (1.f + 0.3275911f * ax);
  float p = t * (0.254829592f +
            t * (-0.284496736f +
            t * (1.421413741f +
            t * (-1.453152027f +
            t * 1.061405429f))));
  float r = 1.f - p * __expf(-ax * ax);
  return __builtin_copysignf(r, x);
}
__device__ __forceinline__ float gelu_exact(float v) {
  return 0.5f * v * (1.f + fast_erff(v * 0.70710678118654752f));
}

// w: [E][R][C] f32 row-major  ->  wt: [E][C][R] bf16
__global__ __launch_bounds__(256) void transpose_w_kernel(const float* __restrict__ w,
                                                          bf16* __restrict__ wt,
                                                          int R, int C) {
  __shared__ float tile[32][33];
  int e = blockIdx.z;
  int c0 = blockIdx.x * 32, r0 = blockIdx.y * 32;
  int tx = threadIdx.x, ty = threadIdx.y;  // 32 x 8
  const float* we = w + (size_t)e * R * C;
  bf16* wte = wt + (size_t)e * R * C;
#pragma unroll
  for (int k = 0; k < 4; ++k) {
    int r = ty + 8 * k;
    tile[r][tx] = we[(size_t)(r0 + r) * C + c0 + tx];
  }
  __syncthreads();
#pragma unroll
  for (int k = 0; k < 4; ++k) {
    int c = ty + 8 * k;
    wte[(size_t)(c0 + c) * R + r0 + tx] = (bf16)tile[tx][c];
  }
}

// ---------------------------------------------------------------- gating
// convert_x fused in (R9); float4-vectorized (R10).
__global__ __launch_bounds__(256) void gating_kernel(const float* __restrict__ x,
                                                     const float* __restrict__ gw,
                                                     const float* __restrict__ gb,
                                                     bf16* __restrict__ xb,
                                                     float* __restrict__ probs,
                                                     float* __restrict__ wts,
                                                     float* __restrict__ ent) {
  int w = threadIdx.x >> 6, l = threadIdx.x & 63;
  int b = blockIdx.x * 4 + w;
  const float* xr = x + (size_t)b * D_;
  bf16* xbr = xb + (size_t)b * D_;
  float acc[E_];
#pragma unroll
  for (int e = 0; e < E_; ++e) acc[e] = 0.f;
#pragma unroll
  for (int j = 0; j < D_ / 256; ++j) {          // 4 iters, float4 per lane
    int d4 = j * 64 + l;
    float4 xv = ((const float4*)xr)[d4];
    bf16x4v o;
    o[0] = (bf16)xv.x; o[1] = (bf16)xv.y; o[2] = (bf16)xv.z; o[3] = (bf16)xv.w;
    ((bf16x4v*)xbr)[d4] = o;
    const float4* g = (const float4*)(gw + (size_t)(d4 * 4) * E_);  // 4 rows x 2 float4
    float xe[4] = {xv.x, xv.y, xv.z, xv.w};
#pragma unroll
    for (int k = 0; k < 4; ++k) {
      float4 g0 = g[k * 2], g1 = g[k * 2 + 1];
      acc[0] += xe[k] * g0.x; acc[1] += xe[k] * g0.y;
      acc[2] += xe[k] * g0.z; acc[3] += xe[k] * g0.w;
      acc[4] += xe[k] * g1.x; acc[5] += xe[k] * g1.y;
      acc[6] += xe[k] * g1.z; acc[7] += xe[k] * g1.w;
    }
  }
#pragma unroll
  for (int off = 32; off; off >>= 1)
#pragma unroll
    for (int e = 0; e < E_; ++e) acc[e] += __shfl_down(acc[e], off);

  if (l == 0) {
    float lg[E_], p[E_];
    float mx = -1e30f;
#pragma unroll
    for (int e = 0; e < E_; ++e) { lg[e] = acc[e] + gb[e]; mx = fmaxf(mx, lg[e]); }
    float s = 0.f;
#pragma unroll
    for (int e = 0; e < E_; ++e) { p[e] = expf(lg[e] - mx); s += p[e]; }
    float inv = 1.f / s;
    float en = 0.f;
#pragma unroll
    for (int e = 0; e < E_; ++e) { p[e] *= inv; en -= p[e] * logf(p[e] + 1e-8f); }
    ent[b] = en;
#pragma unroll
    for (int e = 0; e < E_; ++e) probs[(size_t)b * E_ + e] = p[e];
    int idx[E_]; float ps[E_];
#pragma unroll
    for (int e = 0; e < E_; ++e) { idx[e] = e; ps[e] = p[e]; }
    for (int i = 0; i < E_ - 1; ++i)
      for (int j = 0; j < E_ - 1 - i; ++j)
        if (ps[j] < ps[j + 1]) {
          float tp = ps[j]; ps[j] = ps[j + 1]; ps[j + 1] = tp;
          int ti = idx[j]; idx[j] = idx[j + 1]; idx[j + 1] = ti;
        }
    float cum = 0.f; float mp[E_];
#pragma unroll
    for (int e = 0; e < E_; ++e) mp[e] = 0.f;
    for (int i = 0; i < E_; ++i) {
      cum += ps[i];
      bool m = (cum <= 0.9f) || (i == 0);
      if (m) mp[idx[i]] = ps[i];
    }
    float ssum = 0.f;
#pragma unroll
    for (int e = 0; e < E_; ++e) ssum += mp[e];
    float invs = 1.f / (ssum + 1e-8f);
#pragma unroll
    for (int e = 0; e < E_; ++e) wts[(size_t)b * E_ + e] = mp[e] * invs;
  }
}

// ---------------------------------------------------------------- GEMM mainloop
// Register-staged pipeline (best verified): global_load -> VGPR, ds_write after
// the barrier; loads in flight across a full compute phase. BK=64, 128x128 tile,
// 4 waves 2x2, 32 MFMA/iter. LDS [row][64] bf16 with p^(r&7) chunk swizzle.
// R14 note: 32x32x16 variant measured WORSE (205us, 16.8M bank conflicts —
// operand groups span 32 rows -> 4 lanes/pos -> 4-way; 16x16's 16-row span
// gives the free 2-way). 16x16x32 is the measured optimum shape here.
__device__ __forceinline__ void gemm_loop_rs(const bf16* __restrict__ A,
                                             const bf16* __restrict__ Bt,
                                             int K, int rowBase, int colBase,
                                             bf16* lA, bf16* lB, f32x4 acc[4][4]) {
  const int tid = threadIdx.x;
  const int w = tid >> 6, l = tid & 63;
  const int wm = w >> 1, wn = w & 1;
  const int fm = l & 15, fc = l >> 4;
  const int lr = l >> 3;          // staging row-within-8
  const int lc = l & 7;           // global chunk (contiguous)
  const bf16* gA = A + (size_t)(rowBase + w * 32 + lr) * K + lc * 8;
  const bf16* gB = Bt + (size_t)(colBase + w * 32 + lr) * K + lc * 8;
  const int wp = lc ^ lr;         // LDS chunk position (row&7 == lr)
  bf16* dA = lA + (w * 32 + lr) * 64 + wp * 8;
  bf16* dB = lB + (w * 32 + lr) * 64 + wp * 8;

  bf16x8 ra[4], rb[4];
  const int nIter = K >> 6;
  // prologue: loads for iter 0
#pragma unroll
  for (int i = 0; i < 4; ++i) {
    ra[i] = *(const bf16x8*)(gA + (size_t)(i * 8) * K);
    rb[i] = *(const bf16x8*)(gB + (size_t)(i * 8) * K);
  }
  for (int it = 0; it < nIter; ++it) {
    __syncthreads();                    // prev compute done reading LDS
#pragma unroll
    for (int i = 0; i < 4; ++i) {       // vmcnt wait lands here (covered)
      *(bf16x8*)(dA + i * 512) = ra[i];
      *(bf16x8*)(dB + i * 512) = rb[i];
    }
    if (it + 1 < nIter) {
      const int k0 = (it + 1) << 6;
#pragma unroll
      for (int i = 0; i < 4; ++i) {     // in flight across full compute phase
        ra[i] = *(const bf16x8*)(gA + (size_t)(i * 8) * K + k0);
        rb[i] = *(const bf16x8*)(gB + (size_t)(i * 8) * K + k0);
      }
    }
    __syncthreads();                    // ds_writes visible
#pragma unroll
    for (int kh = 0; kh < 2; ++kh) {
      bf16x8 af[4], bb[4];
#pragma unroll
      for (int mt = 0; mt < 4; ++mt) {
        int r = wm * 64 + mt * 16 + fm;
        int pos = (kh * 4 + fc) ^ (r & 7);
        af[mt] = *(const bf16x8*)(lA + r * 64 + pos * 8);
      }
#pragma unroll
      for (int nt = 0; nt < 4; ++nt) {
        int r = wn * 64 + nt * 16 + fm;
        int pos = (kh * 4 + fc) ^ (r & 7);
        bb[nt] = *(const bf16x8*)(lB + r * 64 + pos * 8);
      }
#pragma unroll
      for (int mt = 0; mt < 4; ++mt)
#pragma unroll
        for (int nt = 0; nt < 4; ++nt)
          acc[mt][nt] = __builtin_amdgcn_mfma_f32_16x16x32_bf16(af[mt], bb[nt], acc[mt][nt], 0, 0, 0);
    }
  }
}

// ------------------------------------------------- v16 path (chunked over B)
// Final configuration (measured optimum across 14 rounds):
//   128x128 tile, reg-staged BK=64 loop, 32 KiB LDS exactly (pow-2 rule ->
//   4 blocks/CU), NC=2/SPLIT=4, col-pinned XCD map, fused gating, parallel
//   esum, 16x16x32 MFMA.
__global__ __launch_bounds__(256, 4) void gemm1_v16_kernel(const bf16* __restrict__ xb,
                                                           const bf16* __restrict__ w1t,
                                                           const float* __restrict__ b1,
                                                           const float* __restrict__ wts,
                                                           bf16* __restrict__ h_chunk,
                                                           float* __restrict__ hsum,
                                                           int rowOffset, int Bc) {
  __shared__ bf16 smem[16384];          // 32 KiB: K-loop lA|lB; epi 128x128 swz
  bf16* lA = smem;
  bf16* lB = smem + 8192;
  f32x4 acc[4][4];
#pragma unroll
  for (int mt = 0; mt < 4; ++mt)
#pragma unroll
    for (int nt = 0; nt < 4; ++nt) acc[mt][nt] = 0.f;

  const int flat = blockIdx.y * 128 + blockIdx.x;
  const int xcd = flat & 7, lin = flat >> 3;
  const int cb = xcd * 16 + (lin & 15);
  const int rb = lin >> 4;
  const int colBase = cb * 128;               // fat col in [0,16384)
  const int rowLocal = rb * 128;
  const int rowGlobal = rowOffset + rowLocal;
  const int e = colBase >> 11;                // == xcd

  gemm_loop_rs(xb, w1t, D_, rowGlobal, colBase, lA, lB, acc);

  const int tid = threadIdx.x;
  const int w = tid >> 6, l = tid & 63;
  const int wm = w >> 1, wn = w & 1;
  const int fm = l & 15, fc = l >> 4;
  bf16* he = h_chunk + (size_t)e * Bc * H_;
  const int hc0 = colBase & (H_ - 1);

  float wgt[4][4];
#pragma unroll
  for (int mt = 0; mt < 4; ++mt)
#pragma unroll
    for (int i = 0; i < 4; ++i) {
      int gr = rowGlobal + wm * 64 + mt * 16 + fc * 4 + i;
      wgt[mt][i] = wts[(size_t)gr * E_ + e];
    }

  __syncthreads();   // K-loop LDS reads done; smem reused as epilogue stage
#pragma unroll
  for (int nt = 0; nt < 4; ++nt) {
    int c = wn * 64 + nt * 16 + fm;             // tile-local col
    float bias = b1[colBase + c];
    float csum = 0.f;
#pragma unroll
    for (int mt = 0; mt < 4; ++mt) {
      int rbse = wm * 64 + mt * 16 + fc * 4;    // tile-local row base
#pragma unroll
      for (int i = 0; i < 4; ++i) {
        int r = rbse + i;
        float v = gelu_exact(acc[mt][nt][i] + bias);
        csum += v;
        smem[(size_t)r * 128 + (((c >> 3) ^ (r & 7)) << 3) + (c & 7)] = (bf16)(v * wgt[mt][i]);
      }
    }
    csum += __shfl_down(csum, 32);
    csum += __shfl_down(csum, 16);
    if (fc == 0) atomicAdd(&hsum[colBase + c], csum);
  }
  __syncthreads();

  // coalesced store: per j, 16 rows x 256 B dense (swizzle-inverted read)
#pragma unroll
  for (int j = 0; j < 8; ++j) {
    int row = j * 16 + (tid >> 4);
    int cchunk = tid & 15;
    bf16x8 v = *(const bf16x8*)(smem + (size_t)row * 128 + (size_t)(cchunk ^ (row & 7)) * 8);
    *(bf16x8*)(he + (size_t)(rowLocal + row) * H_ + hc0 + cchunk * 8) = v;
  }
}

// GEMM2: out_chunk += sum over this split's experts of h_scaled[e] @ w2t[e];
// split s==0 adds the sum_e wts*b2 bias. SPLIT>1 -> f32 atomics (out zeroed).
// Grid (O/128, Bc/128, SPLIT): blockIdx.x == col -> each XCD keeps its w2t
// col-slice (4MB) L2-resident (measured best of 3 mappings).
template <int SPLIT>
__global__ __launch_bounds__(256, 4) void gemm2_v16_kernel(const bf16* __restrict__ h_chunk,
                                                           const bf16* __restrict__ w2t,
                                                           const float* __restrict__ b2,
                                                           const float* __restrict__ wts,
                                                           float* __restrict__ out_chunk,
                                                           int rowOffset, int Bc) {
  __shared__ bf16 smem[16384];
  bf16* lA = smem;
  bf16* lB = smem + 8192;
  f32x4 acc[4][4];
#pragma unroll
  for (int mt = 0; mt < 4; ++mt)
#pragma unroll
    for (int nt = 0; nt < 4; ++nt) acc[mt][nt] = 0.f;

  const int colBase = blockIdx.x * 128;
  const int rowLocal = blockIdx.y * 128;
  const int s = blockIdx.z;
  const int g = E_ / SPLIT, e0 = s * g;

  for (int e = e0; e < e0 + g; ++e)
    gemm_loop_rs(h_chunk + (size_t)e * Bc * H_, w2t + (size_t)e * O_ * H_, H_,
                 rowLocal, colBase, lA, lB, acc);

  const int w = threadIdx.x >> 6, l = threadIdx.x & 63;
  const int wm = w >> 1, wn = w & 1;
  const int fm = l & 15, fc = l >> 4;
#pragma unroll
  for (int nt = 0; nt < 4; ++nt) {
    int gc = colBase + wn * 64 + nt * 16 + fm;
    float b2v[E_];
    if (s == 0) {
#pragma unroll
      for (int e = 0; e < E_; ++e) b2v[e] = b2[(size_t)e * O_ + gc];
    }
#pragma unroll
    for (int mt = 0; mt < 4; ++mt) {
      int lrb = rowLocal + wm * 64 + mt * 16 + fc * 4;
#pragma unroll
      for (int i = 0; i < 4; ++i) {
        int lr2 = lrb + i;
        float v = acc[mt][nt][i];
        if (s == 0) {
          const float4* wr = (const float4*)(wts + (size_t)(rowOffset + lr2) * E_);
          float4 w0 = wr[0], w1v = wr[1];
          v += w0.x * b2v[0] + w0.y * b2v[1] + w0.z * b2v[2] + w0.w * b2v[3] +
               w1v.x * b2v[4] + w1v.y * b2v[5] + w1v.z * b2v[6] + w1v.w * b2v[7];
        }
        float* op = out_chunk + (size_t)lr2 * O_ + gc;
        if (SPLIT == 1) *op = v;
        else atomicAdd(op, v);
      }
    }
  }
}

// esum2[e][o] += hsum[e, seg] . w2[e, seg, o]  (parallel over 8 H-segments;
// esum2 zeroed first).
__global__ __launch_bounds__(256) void esum_v2_kernel(const float* __restrict__ hsum,
                                                      const float* __restrict__ w2,
                                                      float* __restrict__ esum2) {
  const int e = blockIdx.y;
  const int o = blockIdx.x * 256 + threadIdx.x;
  const int h0 = blockIdx.z * (H_ / 8);
  const float* w2e = w2 + (size_t)e * H_ * O_;
  const float* hs = hsum + (size_t)e * H_;
  float a0 = 0.f, a1 = 0.f;
  for (int h = h0; h < h0 + H_ / 8; h += 2) {
    a0 += hs[h] * w2e[(size_t)h * O_ + o];
    a1 += hs[h + 1] * w2e[(size_t)(h + 1) * O_ + o];
  }
  atomicAdd(&esum2[(size_t)e * O_ + o], a0 + a1);
}

// ---------------------------------------------------------------- fallback GEMMs
__device__ __forceinline__ void gemm_loop(const bf16* __restrict__ A,
                                          const bf16* __restrict__ Bt,
                                          int K, int rowBase, int colBase,
                                          bf16* lA, bf16* lB, f32x4 acc[4][4]) {
  const int tid = threadIdx.x;
  const int w = tid >> 6, l = tid & 63;
  const int wm = w >> 1, wn = w & 1;
  const int fm = l & 15, fc = l >> 4;
  const int lr = l >> 2, lc = l & 3;
  const int sr0 = (w * 2 + 0) * 16 + lr;
  const int sr1 = (w * 2 + 1) * 16 + lr;
  const int cg0 = lc ^ ((sr0 >> 1) & 3);
  const int cg1 = lc ^ ((sr1 >> 1) & 3);
  const bf16* gA0 = A + (size_t)(rowBase + sr0) * K + cg0 * 8;
  const bf16* gA1 = A + (size_t)(rowBase + sr1) * K + cg1 * 8;
  const bf16* gB0 = Bt + (size_t)(colBase + sr0) * K + cg0 * 8;
  const bf16* gB1 = Bt + (size_t)(colBase + sr1) * K + cg1 * 8;
  bf16* lA0 = lA + (w * 2 + 0) * 512;
  bf16* lA1 = lA + (w * 2 + 1) * 512;
  bf16* lB0 = lB + (w * 2 + 0) * 512;
  bf16* lB1 = lB + (w * 2 + 1) * 512;

  for (int k0 = 0; k0 < K; k0 += 32) {
    __syncthreads();
    gload16(gA0 + k0, lA0);
    gload16(gA1 + k0, lA1);
    gload16(gB0 + k0, lB0);
    gload16(gB1 + k0, lB1);
    __syncthreads();

    bf16x8 af[4], bb[4];
#pragma unroll
    for (int mt = 0; mt < 4; ++mt) {
      int r = wm * 64 + mt * 16 + fm;
      af[mt] = *(const bf16x8*)(lA + (size_t)(r * 4 + (fc ^ ((r >> 1) & 3))) * 8);
    }
#pragma unroll
    for (int nt = 0; nt < 4; ++nt) {
      int r = wn * 64 + nt * 16 + fm;
      bb[nt] = *(const bf16x8*)(lB + (size_t)(r * 4 + (fc ^ ((r >> 1) & 3))) * 8);
    }
#pragma unroll
    for (int mt = 0; mt < 4; ++mt)
#pragma unroll
      for (int nt = 0; nt < 4; ++nt)
        acc[mt][nt] = __builtin_amdgcn_mfma_f32_16x16x32_bf16(af[mt], bb[nt], acc[mt][nt], 0, 0, 0);
  }
}

__global__ __launch_bounds__(256) void gemm1_gelu_kernel(const bf16* __restrict__ xb,
                                                         const bf16* __restrict__ w1te,
                                                         const float* __restrict__ b1e,
                                                         bf16* __restrict__ h) {
  __shared__ bf16 lA[128 * 32];
  __shared__ bf16 lB[128 * 32];
  f32x4 acc[4][4];
#pragma unroll
  for (int mt = 0; mt < 4; ++mt)
#pragma unroll
    for (int nt = 0; nt < 4; ++nt) acc[mt][nt] = 0.f;

  int rowBase = blockIdx.y * 128, colBase = blockIdx.x * 128;
  gemm_loop(xb, w1te, D_, rowBase, colBase, lA, lB, acc);

  const int w = threadIdx.x >> 6, l = threadIdx.x & 63;
  const int wm = w >> 1, wn = w & 1;
#pragma unroll
  for (int mt = 0; mt < 4; ++mt)
#pragma unroll
    for (int nt = 0; nt < 4; ++nt) {
      int gc = colBase + wn * 64 + nt * 16 + (l & 15);
      float bias = b1e[gc];
#pragma unroll
      for (int i = 0; i < 4; ++i) {
        int gr = rowBase + wm * 64 + mt * 16 + (l >> 4) * 4 + i;
        float v = gelu_exact(acc[mt][nt][i] + bias);
        h[(size_t)gr * H_ + gc] = (bf16)v;
      }
    }
}

__global__ __launch_bounds__(256) void gemm2_fused_kernel(const bf16* __restrict__ h,
                                                          const bf16* __restrict__ w2te,
                                                          const float* __restrict__ b2e,
                                                          const float* __restrict__ wts,
                                                          int e,
                                                          float* __restrict__ out,
                                                          float* __restrict__ esum) {
  __shared__ bf16 lA[128 * 32];
  __shared__ bf16 lB[128 * 32];
  f32x4 acc[4][4];
#pragma unroll
  for (int mt = 0; mt < 4; ++mt)
#pragma unroll
    for (int nt = 0; nt < 4; ++nt) acc[mt][nt] = 0.f;

  int rowBase = blockIdx.y * 128, colBase = blockIdx.x * 128;
  gemm_loop(h, w2te, H_, rowBase, colBase, lA, lB, acc);

  const int w = threadIdx.x >> 6, l = threadIdx.x & 63;
  const int wm = w >> 1, wn = w & 1;
#pragma unroll
  for (int nt = 0; nt < 4; ++nt) {
    int gc = colBase + wn * 64 + nt * 16 + (l & 15);
    float bias = b2e[gc];
    float csum = 0.f;
#pragma unroll
    for (int mt = 0; mt < 4; ++mt) {
      int grb = rowBase + wm * 64 + mt * 16 + (l >> 4) * 4;
#pragma unroll
      for (int i = 0; i < 4; ++i) {
        int gr = grb + i;
        float v = acc[mt][nt][i] + bias;
        csum += v;
        float wgt = wts[(size_t)gr * E_ + e];
        float* op = out + (size_t)gr * O_ + gc;
        *op += wgt * v;
      }
    }
    csum += __shfl_down(csum, 32);
    csum += __shfl_down(csum, 16);
    if ((l >> 4) == 0) atomicAdd(&esum[(size_t)e * O_ + gc], csum);
  }
}

// ---------------------------------------------------------------- losses
// MODE 0: expert_mean = esum/B (bias included). MODE 1: esum/B + b2.
template <int MODE>
__global__ __launch_bounds__(256) void scalars_kernel(const float* __restrict__ probs,
                                                      const float* __restrict__ ent,
                                                      const float* __restrict__ esum,
                                                      const float* __restrict__ b2,
                                                      float* __restrict__ outs) {
  __shared__ float red[256];
  __shared__ float Vsh[E_][O_ + 8];
  __shared__ float mp_sh[E_], norm_sh[E_];
  __shared__ float gram[E_][E_];
  int t = threadIdx.x;

  float s = 0.f;
  for (int i = t; i < B_; i += 256) s += ent[i];
  red[t] = s; __syncthreads();
  for (int off = 128; off; off >>= 1) { if (t < off) red[t] += red[t + off]; __syncthreads(); }
  if (t == 0) outs[0] = red[0] / (float)B_;
  __syncthreads();

  float mp[E_];
#pragma unroll
  for (int e = 0; e < E_; ++e) mp[e] = 0.f;
  for (int i = t; i < B_; i += 256) {
#pragma unroll
    for (int e = 0; e < E_; ++e) mp[e] += probs[(size_t)i * E_ + e];
  }
  for (int e = 0; e < E_; ++e) {
    red[t] = mp[e]; __syncthreads();
    for (int off = 128; off; off >>= 1) { if (t < off) red[t] += red[t + off]; __syncthreads(); }
    if (t == 0) mp_sh[e] = red[0] / (float)B_;
    __syncthreads();
  }

  for (int e = 0; e < E_; ++e) {
    float ss = 0.f;
    for (int o = t; o < O_; o += 256) {
      float m = esum[(size_t)e * O_ + o] / (float)B_;
      if (MODE == 1) m += b2[(size_t)e * O_ + o];
      ss += m * m;
    }
    red[t] = ss; __syncthreads();
    for (int off = 128; off; off >>= 1) { if (t < off) red[t] += red[t + off]; __syncthreads(); }
    if (t == 0) norm_sh[e] = sqrtf(red[0]) + 1e-6f;
    __syncthreads();
  }

  for (int e = 0; e < E_; ++e)
    for (int o = t; o < O_; o += 256) {
      float m = esum[(size_t)e * O_ + o] / (float)B_;
      if (MODE == 1) m += b2[(size_t)e * O_ + o];
      Vsh[e][o] = mp_sh[e] * m / norm_sh[e];
    }
  __syncthreads();

  {
    // 256 threads: pair p = t>>2 (i=p>>3, j=p&7), sub-range sub = t&3 over O/4.
    int pair = t >> 2, sub = t & 3;
    int i = pair >> 3, j = pair & 7;
    float g = 0.f;
    for (int o = sub * (O_ / 4); o < (sub + 1) * (O_ / 4); ++o)
      g += Vsh[i][o] * Vsh[j][o];
    red[t] = g; __syncthreads();
    if (sub == 0) {
      float gg = red[t] + red[t + 1] + red[t + 2] + red[t + 3];
      if (i == j) gg += 1e-6f;
      gram[i][j] = gg;
    }
  }
  __syncthreads();

  if (t == 0) {
    double a[E_][E_];
    for (int i = 0; i < E_; ++i) for (int j = 0; j < E_; ++j) a[i][j] = (double)gram[i][j];
    double ld = 0.0;
    for (int k = 0; k < E_; ++k) {
      int p = k; double mx = fabs(a[k][k]);
      for (int i = k + 1; i < E_; ++i) if (fabs(a[i][k]) > mx) { mx = fabs(a[i][k]); p = i; }
      if (p != k) for (int j = 0; j < E_; ++j) { double tmp = a[k][j]; a[k][j] = a[p][j]; a[p][j] = tmp; }
      ld += log(fabs(a[k][k]));
      double inv = 1.0 / a[k][k];
      for (int i = k + 1; i < E_; ++i) {
        double f = a[i][k] * inv;
        for (int j = k; j < E_; ++j) a[i][j] -= f * a[k][j];
      }
    }
    outs[1] = (float)(-ld);
  }
}

// ---------------------------------------------------------------- launch
extern "C" void kernel_launch(void* const* d_in, const int* in_sizes, int n_in,
                              void* d_out, int out_size, void* d_ws, size_t ws_size,
                              hipStream_t stream) {
  const float* x  = (const float*)d_in[0];
  const float* gw = (const float*)d_in[1];
  const float* gb = (const float*)d_in[2];
  const float* w1 = (const float*)d_in[3];
  const float* b1 = (const float*)d_in[4];
  const float* w2 = (const float*)d_in[5];
  const float* b2 = (const float*)d_in[6];
  float* out = (float*)d_out;

  char* ws = (char*)d_ws;
  size_t need = 0;
  bf16* xb    = (bf16*)(ws + need); need += (size_t)B_ * D_ * 2;
  bf16* w1t   = (bf16*)(ws + need); need += (size_t)E_ * D_ * H_ * 2;
  bf16* w2t   = (bf16*)(ws + need); need += (size_t)E_ * H_ * O_ * 2;
  float* wts  = (float*)(ws + need); need += (size_t)B_ * E_ * 4;
  float* probs= (float*)(ws + need); need += (size_t)B_ * E_ * 4;
  float* ent  = (float*)(ws + need); need += (size_t)B_ * 4;
  float* hsum = (float*)(ws + need); need += (size_t)E_ * H_ * 4;
  float* esum = (float*)(ws + need); need += (size_t)E_ * O_ * 4;
  size_t need_common = need;
  bf16* h_chunk = (bf16*)(ws + need);

  // NC preference 2 (measured optimum); fallbacks 4, 8, 1.
  int NC = 0;
  const int prefs[4] = {2, 4, 8, 1};
  for (int i = 0; i < 4; ++i) {
    int nc = prefs[i];
    size_t tot = need_common + (size_t)E_ * (B_ / nc) * H_ * 2;
    if (ws_size >= tot) { NC = nc; break; }
  }

  transpose_w_kernel<<<dim3(H_ / 32, D_ / 32, E_), dim3(32, 8), 0, stream>>>(w1, w1t, D_, H_);
  transpose_w_kernel<<<dim3(O_ / 32, H_ / 32, E_), dim3(32, 8), 0, stream>>>(w2, w2t, H_, O_);
  gating_kernel<<<B_ / 4, 256, 0, stream>>>(x, gw, gb, xb, probs, wts, ent);

  if (NC > 0) {
    const int Bc = B_ / NC;
    const int SPLIT = (NC == 1) ? 2 : (NC == 2) ? 4 : 8;
    // hsum and esum are adjacent in the workspace: one memset covers both.
    hipMemsetAsync(hsum, 0, (size_t)E_ * H_ * sizeof(float) + (size_t)E_ * O_ * sizeof(float), stream);
    hipMemsetAsync(out, 0, (size_t)B_ * O_ * sizeof(float), stream);
    for (int c = 0; c < NC; ++c) {
      int rowOffset = c * Bc;
      gemm1_v16_kernel<<<dim3(128, Bc / 128), 256, 0, stream>>>(
          xb, w1t, b1, wts, h_chunk, hsum, rowOffset, Bc);
      float* out_chunk = out + (size_t)rowOffset * O_;
      dim3 g2(O_ / 128, Bc / 128, SPLIT);
      switch (SPLIT) {
        case 2: gemm2_v16_kernel<2><<<g2, 256, 0, stream>>>(h_chunk, w2t, b2, wts, out_chunk, rowOffset, Bc); break;
        case 4: gemm2_v16_kernel<4><<<g2, 256, 0, stream>>>(h_chunk, w2t, b2, wts, out_chunk, rowOffset, Bc); break;
        case 8: gemm2_v16_kernel<8><<<g2, 256, 0, stream>>>(h_chunk, w2t, b2, wts, out_chunk, rowOffset, Bc); break;
      }
    }
    esum_v2_kernel<<<dim3(O_ / 256, E_, 8), 256, 0, stream>>>(hsum, w2, esum);
    scalars_kernel<1><<<1, 256, 0, stream>>>(probs, ent, esum, b2, out + (size_t)B_ * O_);
  } else {
    bf16* he = (bf16*)(ws + need_common);
    if (ws_size < need_common + (size_t)B_ * H_ * 2) return;
    hipMemsetAsync(out, 0, (size_t)B_ * O_ * sizeof(float), stream);
    hipMemsetAsync(esum, 0, (size_t)E_ * O_ * sizeof(float), stream);
    for (int e = 0; e < E_; ++e) {
      gemm1_gelu_kernel<<<dim3(H_ / 128, B_ / 128), 256, 0, stream>>>(
          xb, w1t + (size_t)e * H_ * D_, b1 + (size_t)e * H_, he);
      gemm2_fused_kernel<<<dim3(O_ / 128, B_ / 128), 256, 0, stream>>>(
          he, w2t + (size_t)e * O_ * H_, b2 + (size_t)e * O_, wts, e, out, esum);
    }
    scalars_kernel<0><<<1, 256, 0, stream>>>(probs, ent, esum, b2, out + (size_t)B_ * O_);
  }
}